// Round 8
// baseline (1596.634 us; speedup 1.0000x reference)
//
#include <hip/hip_runtime.h>
#include <math.h>

#define BSZ 64
#define TLEN 256
#define LSND 65536
#define ZK 160            // z K-length in bf16 slots: 129 real + iv-residual@129 + pads

typedef __attribute__((ext_vector_type(8))) short bf16x8;
typedef __attribute__((ext_vector_type(4))) float f32x4;

__device__ __forceinline__ float sigm(float x) { return 1.f / (1.f + __expf(-x)); }
__device__ __forceinline__ float tanh_f(float x) {
  float e = __expf(-2.f * fabsf(x));
  return copysignf((1.f - e) / (1.f + e), x);
}
__device__ __forceinline__ unsigned short f2bf(float x) {   // RNE f32->bf16
  unsigned u = __float_as_uint(x);
  return (unsigned short)((u + 0x7FFFu + ((u >> 16) & 1u)) >> 16);
}
__device__ __forceinline__ f32x4 unpack4(unsigned long long v) {
  f32x4 r;
  r[0] = __uint_as_float((unsigned)(v & 0xFFFFu) << 16);
  r[1] = __uint_as_float((unsigned)((v >> 16) & 0xFFFFu) << 16);
  r[2] = __uint_as_float((unsigned)((v >> 32) & 0xFFFFu) << 16);
  r[3] = __uint_as_float((unsigned)((v >> 48) & 0xFFFFu) << 16);
  return r;
}
// weight-row permutation: tile row m -> (jl=m>>2, gate=m&3); n = gate*256 + q*4 + jl
__device__ __forceinline__ int nrow(int q, int m) {
  return ((m & 3) << 8) + (q << 2) + (m >> 2);
}

// K1: fold linear into w_ih: Wc[n][j] (1024x132, cols>=129 zero); bc = folded bias
__global__ __launch_bounds__(256) void prep_kernel(
    const float* __restrict__ w_ih, const float* __restrict__ lin_w,
    const float* __restrict__ lin_b, const float* __restrict__ b_ih,
    const float* __restrict__ b_hh, float* __restrict__ Wc, float* __restrict__ bc)
{
  __shared__ float sRow[256];
  const int n = blockIdx.x;
  const int j = threadIdx.x;
  sRow[j] = w_ih[n * 256 + j];
  __syncthreads();
  if (j < 132) {
    float acc = 0.f;
    if (j < 129) {
      for (int k = 0; k < 256; ++k) acc += sRow[k] * lin_w[k * 129 + j];
    }
    Wc[n * 132 + j] = acc;
  } else if (j == 255) {
    float acc = b_ih[n] + b_hh[n];
    for (int k = 0; k < 256; ++k) acc += sRow[k] * lin_b[k];
    bc[n] = acc;
  }
}

__global__ __launch_bounds__(256) void transpose_w3(const float* __restrict__ w3,
                                                    float* __restrict__ w3t)
{
  int i = blockIdx.x * 256 + threadIdx.x;
  if (i < 96 * 128) { int s = i >> 7, o = i & 127; w3t[i] = w3[o * 96 + s]; }
}

// K1c: pack Wc into MFMA-A-frag chunks (bf16) + permuted bias
// Wcperm chunk id = (q*5+o)*64 + m*4 + kg  (16B = 8 bf16, k = o*32+kg*8+e)
__global__ __launch_bounds__(256) void pack_wc(
    const float* __restrict__ Wc, const float* __restrict__ bc,
    unsigned short* __restrict__ Wcperm, float* __restrict__ bcp)
{
  const int cid = blockIdx.x * 256 + threadIdx.x;
  if (cid >= 64 * 5 * 64) return;
  const int q = cid / 320, rem = cid - q * 320;
  const int o = rem >> 6, l = rem & 63;
  const int m = l >> 2, kg = l & 3;
  const int n = nrow(q, m);
  unsigned short out[8];
  #pragma unroll
  for (int e = 0; e < 8; ++e) {
    const int kz = o * 32 + kg * 8 + e;
    float v = (kz < 129) ? Wc[n * 132 + kz] : (kz == 129 ? Wc[n * 132] : 0.f);
    out[e] = f2bf(v);
  }
  *(ulonglong2*)(Wcperm + cid * 8) = *(ulonglong2*)out;
  if (o == 0 && kg == 0) bcp[q * 16 + m] = bc[n];
}

// K1d: pack w_hh into A-frag chunks: chunk id = ((q*8+o)*16+m)*4+kg
__global__ __launch_bounds__(256) void pack_whh(
    const float* __restrict__ whh, unsigned short* __restrict__ whhp)
{
  const int cid = blockIdx.x * 256 + threadIdx.x;   // < 32768
  const int q = cid >> 9, rem = cid & 511;
  const int o = rem >> 6, l = rem & 63;
  const int m = l >> 2, kg = l & 3;
  const int n = nrow(q, m);
  unsigned short out[8];
  #pragma unroll
  for (int e = 0; e < 8; ++e)
    out[e] = f2bf(whh[n * 256 + o * 32 + kg * 8 + e]);
  *(ulonglong2*)(whhp + cid * 8) = *(ulonglong2*)out;
}

// K2: gather + conv1/conv2/conv3 -> zw[t][b][ZK] bf16 (unchanged from R7).
__global__ __launch_bounds__(64) void conv_kernel(
    const int* __restrict__ alpha, const float* __restrict__ sound,
    const float* __restrict__ w1, const float* __restrict__ b1v,
    const float* __restrict__ w2, const float* __restrict__ b2,
    const float* __restrict__ w3t, const float* __restrict__ b3,
    unsigned short* __restrict__ zw)
{
  __shared__ float win[2048];
  __shared__ float sY2[96];
  const int l = threadIdx.x;
  const int b = blockIdx.x >> 8;
  const int t = blockIdx.x & 255;
  const int a = alpha[b * TLEN + t];
  const int a0 = a - 1024;
  const float* srow = sound + (size_t)b * LSND;
  for (int x = l; x < 2048; x += 64) {
    int p = a0 + x;
    win[x] = (p >= 0 && p < LSND) ? srow[p] : 0.f;
  }
  __syncthreads();
  float acc0 = 0.f, acc1 = 0.f, acc2 = 0.f;
  for (int f = l; f < 2046; f += 64) {
    float wv = w1[f];
    acc0 += win[f] * wv;
    acc1 += win[f + 1] * wv;
    acc2 += win[f + 2] * wv;
  }
  for (int m = 32; m; m >>= 1) {
    acc0 += __shfl_xor(acc0, m);
    acc1 += __shfl_xor(acc1, m);
    acc2 += __shfl_xor(acc2, m);
  }
  const float bb = b1v[0];
  const float y11 = acc0 + bb, y12 = acc1 + bb, y13 = acc2 + bb;
  {
    int s = l;
    int c = s / 3, lp = s - c * 3;
    float wA = w2[c * 3], wB = w2[c * 3 + 1], wC = w2[c * 3 + 2];
    float v = (lp == 0) ? (y11 * wB + y12 * wC)
            : (lp == 1) ? (y11 * wA + y12 * wB + y13 * wC)
                        : (y12 * wA + y13 * wB);
    sY2[s] = fmaxf(v + b2[c], 0.f);
    if (l < 32) {
      s = 64 + l; c = s / 3; lp = s - c * 3;
      wA = w2[c * 3]; wB = w2[c * 3 + 1]; wC = w2[c * 3 + 2];
      v = (lp == 0) ? (y11 * wB + y12 * wC)
        : (lp == 1) ? (y11 * wA + y12 * wB + y13 * wC)
                    : (y12 * wA + y13 * wB);
      sY2[s] = fmaxf(v + b2[c], 0.f);
    }
  }
  __syncthreads();
  float o0 = b3[l], o1 = b3[l + 64];
  for (int s = 0; s < 96; ++s) {
    float yv = sY2[s];
    o0 += yv * w3t[s * 128 + l];
    o1 += yv * w3t[s * 128 + l + 64];
  }
  unsigned short* zrow = zw + ((size_t)t * BSZ + b) * ZK;
  zrow[1 + l] = f2bf(o0);
  zrow[65 + l] = f2bf(o1);
  if (l == 0) {
    int prev = (t > 0) ? alpha[b * TLEN + t - 1] : 0;
    float iv = (float)(a - prev);
    unsigned short hi = f2bf(iv);
    zrow[0] = hi;
    float rec = __uint_as_float(((unsigned)hi) << 16);
    zrow[129] = f2bf(iv - rec);
  }
  if (l < 30) zrow[130 + l] = 0;
}

// K2b: xw GEMM — xw[t][b][n] = z.Wc^T + bc for all t (no recurrence), bf16 out,
// laid out frag-linear: 16B chunk c = q*32 + bl*2 + (kg>>1), within [t][bt] 32KB.
__global__ __launch_bounds__(256) void xw_gemm(
    const unsigned short* __restrict__ zw, const unsigned short* __restrict__ Wcperm,
    const float* __restrict__ bcp, unsigned short* __restrict__ xwp)
{
  const int t = (int)blockIdx.x >> 2;
  const int bt = (int)blockIdx.x & 3;
  const int tid = threadIdx.x;
  const int w = tid >> 6, ln = tid & 63;
  const int bl = ln & 15, kg = ln >> 4;

  bf16x8 zf[5];
  #pragma unroll
  for (int o = 0; o < 5; ++o)
    zf[o] = *(const bf16x8*)(zw + ((size_t)t * BSZ + (bt << 4) + bl) * ZK + o * 32 + kg * 8);

  #pragma unroll 2
  for (int qq = 0; qq < 16; ++qq) {
    const int q = (w << 4) + qq;
    f32x4 acc = *(const f32x4*)(bcp + q * 16 + (kg << 2));
    #pragma unroll
    for (int o = 0; o < 5; ++o) {
      bf16x8 af = *(const bf16x8*)(Wcperm + ((size_t)(q * 5 + o) * 64 + (bl << 2) + kg) * 8);
      acc = __builtin_amdgcn_mfma_f32_16x16x32_bf16(af, zf[o], acc, 0, 0, 0);
    }
    uint2 pk;
    pk.x = (unsigned)f2bf(acc[0]) | ((unsigned)f2bf(acc[1]) << 16);
    pk.y = (unsigned)f2bf(acc[2]) | ((unsigned)f2bf(acc[3]) << 16);
    char* dst = (char*)xwp + (((size_t)t * 4 + bt) << 15)
              + ((q * 32 + bl * 2 + (kg >> 1)) << 4) + ((kg & 1) << 3);
    *(uint2*)dst = pk;
  }
}

// K3: single-CU-per-batch-group LSTM. 4 blocks x 512 thr (8 waves, <=256 VGPR).
// w_hh A-frags: 54/wave in VGPRs + 10/wave in LDS (80KB). h double-buffered in
// 16KB LDS (XOR-swizzled 16B slots, R7-proven pattern). xw(t) staged in 32KB LDS
// via global_load_lds issued one step ahead (per-wave-private regions -> no sync
// beyond the one per-step barrier, which also drains vmcnt). Gate math lane-local.
// Zero inter-block traffic, zero atomics.
__global__ void __launch_bounds__(512, 2) lstm_kernel(
    const unsigned short* __restrict__ whhp, const unsigned short* __restrict__ xwp,
    float* __restrict__ hfin)
{
  __shared__ unsigned short sW[8 * 10 * 64 * 8];   // 81920 B
  __shared__ unsigned short sH[2 * 16 * 256];      // 16384 B
  __shared__ unsigned short sX[8 * 4 * 64 * 8];    // 32768 B  (total 128 KiB)

  const int tid = threadIdx.x;
  const int w = tid >> 6, ln = tid & 63;
  const int bl = ln & 15, kg = ln >> 4;
  const int bt = (int)blockIdx.x;
  const int b = (bt << 4) + bl;
  char* sHb = (char*)sH;
  char* sXb = (char*)sX;
  char* sWb = (char*)sW;

  // ---- one-time: weight frags -> 54 VGPR frags + 10 LDS frags per wave ----
  bf16x8 wr[54];
  #pragma unroll
  for (int i = 0; i < 8; ++i) {
    #pragma unroll
    for (int o = 0; o < 8; ++o) {
      const int q = (w << 3) + i;
      const bf16x8 v = *(const bf16x8*)(whhp + (((size_t)(q * 8 + o) * 16 + bl) * 4 + kg) * 8);
      if (i >= 2 || (i == 1 && o >= 2)) {
        wr[i * 8 + o - 10] = v;
      } else {
        const int fi = (i == 0) ? o : (8 + o);
        *(bf16x8*)(sWb + (((w * 10 + fi) << 6) + ln) * 16) = v;
      }
    }
  }
  // zero h parity-0 (8KB)
  for (int idx = tid; idx < 2048; idx += 512) ((unsigned*)sHb)[idx] = 0;
  // async stage xw(t=0) into this wave's private sX region
  {
    const char* gsrc = (const char*)xwp + ((size_t)bt << 15) + ((w << 2) << 10) + (ln << 4);
    #pragma unroll
    for (int k = 0; k < 4; ++k)
      __builtin_amdgcn_global_load_lds(
          (const unsigned int*)(gsrc + (k << 10)),
          (unsigned int*)(sXb + (((w << 2) + k) << 10)), 16, 0, 0);
  }
  float c[8] = {0.f, 0.f, 0.f, 0.f, 0.f, 0.f, 0.f, 0.f};

  #pragma unroll 1
  for (int t = 0; t < TLEN; ++t) {
    __syncthreads();                         // h(t) visible; vmcnt drained -> xw(t) in sX
    const int rpo = (t & 1) << 13;           // h read-parity byte offset
    const int wpo = rpo ^ 8192;              // h write-parity
    #pragma unroll
    for (int g = 0; g < 4; ++g) {
      // acc init from xw (2 tiles: i0=2g, i1=2g+1)
      const int cb0 = (((w << 8) + (g << 6) + (bl << 1) + (kg >> 1)) << 4) + ((kg & 1) << 3);
      const unsigned long long xv0 = *(const unsigned long long*)(sXb + cb0);
      const unsigned long long xv1 = *(const unsigned long long*)(sXb + cb0 + 512);
      f32x4 acc0 = unpack4(xv0);
      f32x4 acc1 = unpack4(xv1);
      // refill this region with xw(t+1) (reads above are complete after waitcnt)
      if (t < TLEN - 1) {
        asm volatile("s_waitcnt lgkmcnt(0)" ::: "memory");
        __builtin_amdgcn_sched_barrier(0);
        const char* gsrc = (const char*)xwp + (((size_t)(t + 1) * 4 + bt) << 15)
                         + (((w << 2) + g) << 10) + (ln << 4);
        __builtin_amdgcn_global_load_lds(
            (const unsigned int*)gsrc,
            (unsigned int*)(sXb + (((w << 2) + g) << 10)), 16, 0, 0);
      }
      // K=256 MFMA: h frags from LDS, weights from regs/LDS
      #pragma unroll
      for (int o = 0; o < 8; ++o) {
        const bf16x8 hf = *(const bf16x8*)(sHb + rpo + (bl << 9) + ((((o << 2) + kg) ^ bl) << 4));
        bf16x8 a0, a1;
        if (g == 0) {
          a0 = *(const bf16x8*)(sWb + (((w * 10 + o) << 6) + ln) * 16);
          if (o < 2) a1 = *(const bf16x8*)(sWb + (((w * 10 + 8 + o) << 6) + ln) * 16);
          else       a1 = wr[8 + o - 10];
        } else {
          a0 = wr[(2 * g) * 8 + o - 10];
          a1 = wr[(2 * g + 1) * 8 + o - 10];
        }
        acc0 = __builtin_amdgcn_mfma_f32_16x16x32_bf16(a0, hf, acc0, 0, 0, 0);
        acc1 = __builtin_amdgcn_mfma_f32_16x16x32_bf16(a1, hf, acc1, 0, 0, 0);
      }
      // gates (lane-local: lane owns (b=bl, j) with all 4 gates in acc regs)
      #pragma unroll
      for (int ii = 0; ii < 2; ++ii) {
        const int i = 2 * g + ii;
        const f32x4 A = ii ? acc1 : acc0;
        c[i] = sigm(A[1]) * c[i] + sigm(A[0]) * tanh_f(A[2]);
        const float hv = sigm(A[3]) * tanh_f(c[i]);
        const int j = (w << 5) + (i << 2) + kg;
        if (t < TLEN - 1) {
          const int sl = j >> 3;
          *(unsigned short*)(sHb + wpo + (bl << 9) + ((sl ^ bl) << 4) + ((j & 7) << 1)) = f2bf(hv);
        } else {
          hfin[b * 256 + j] = hv;
        }
      }
    }
  }
}

// ------- fallback (ws too small): R7 mailbox LSTM, verbatim -------
__global__ void __launch_bounds__(512, 2) lstm_mailbox(
    const unsigned short* __restrict__ zw, const float* __restrict__ Wc,
    const float* __restrict__ bc, const float* __restrict__ w_hh,
    unsigned long long* __restrict__ hq, float* __restrict__ hfin)
{
  __shared__ uint4 sH[2][16][32];
  char* sHb = (char*)&sH[0][0][0];
  const int tid = threadIdx.x;
  const int w  = tid >> 6;
  const int ln = tid & 63;
  const int bl = ln & 15;
  const int kg = ln >> 4;
  const int jt = (int)blockIdx.x & 3;
  const int bt = (int)blockIdx.x >> 2;
  const int b  = (bt << 4) + bl;

  bf16x8 afr[2][13];
  #pragma unroll
  for (int a = 0; a < 2; ++a) {
    const int jloc = ((w << 1) + a) * 4 + (bl >> 2);
    const int grow = (bl & 3) * 256 + jt * 64 + jloc;
    #pragma unroll
    for (int o = 0; o < 13; ++o) {
      #pragma unroll
      for (int e = 0; e < 8; ++e) {
        const int k = o * 32 + kg * 8 + e;
        float wt;
        if (k < 256) wt = w_hh[grow * 256 + k];
        else {
          const int kz = k - 256;
          wt = (kz < 129) ? Wc[grow * 132 + kz] : (kz == 129 ? Wc[grow * 132] : 0.f);
        }
        afr[a][o][e] = (short)f2bf(wt);
      }
    }
  }
  float bias[2][4];
  #pragma unroll
  for (int a = 0; a < 2; ++a)
    #pragma unroll
    for (int r = 0; r < 4; ++r)
      bias[a][r] = bc[r * 256 + jt * 64 + ((w << 1) + a) * 4 + kg];

  const int bloc = tid >> 5;
  const int oct  = tid & 31;
  const int pollbase = ((bt << 4) + bloc) * 128 + (oct << 2);
  char* ldsW = sHb + (bloc << 9) + (((oct ^ bloc) & 31) << 4);
  float cs[2] = {0.f, 0.f};

  #pragma unroll 1
  for (int t = 0; t < TLEN; ++t) {
    const int parity = (t & 1) << 13;
    const int bufR = t % 3, bufW = (t + 1) % 3;
    bf16x8 zf[5];
    #pragma unroll
    for (int oz = 0; oz < 5; ++oz)
      zf[oz] = *(const bf16x8*)(zw + ((size_t)t * BSZ + b) * ZK + oz * 32 + kg * 8);
    {
      const unsigned long long* hs = hq + (size_t)bufR * 8192 + pollbase;
      const unsigned tagw = (unsigned)t;
      unsigned long long v0, v1, v2, v3;
      v0 = __hip_atomic_load(hs + 0, __ATOMIC_RELAXED, __HIP_MEMORY_SCOPE_AGENT);
      v1 = __hip_atomic_load(hs + 1, __ATOMIC_RELAXED, __HIP_MEMORY_SCOPE_AGENT);
      v2 = __hip_atomic_load(hs + 2, __ATOMIC_RELAXED, __HIP_MEMORY_SCOPE_AGENT);
      v3 = __hip_atomic_load(hs + 3, __ATOMIC_RELAXED, __HIP_MEMORY_SCOPE_AGENT);
      for (;;) {
        bool ok = true;
        if ((unsigned)(v0 >> 32) != tagw) {
          v0 = __hip_atomic_load(hs + 0, __ATOMIC_RELAXED, __HIP_MEMORY_SCOPE_AGENT); ok = false; }
        if ((unsigned)(v1 >> 32) != tagw) {
          v1 = __hip_atomic_load(hs + 1, __ATOMIC_RELAXED, __HIP_MEMORY_SCOPE_AGENT); ok = false; }
        if ((unsigned)(v2 >> 32) != tagw) {
          v2 = __hip_atomic_load(hs + 2, __ATOMIC_RELAXED, __HIP_MEMORY_SCOPE_AGENT); ok = false; }
        if ((unsigned)(v3 >> 32) != tagw) {
          v3 = __hip_atomic_load(hs + 3, __ATOMIC_RELAXED, __HIP_MEMORY_SCOPE_AGENT); ok = false; }
        if (ok) break;
      }
      uint4 pay;
      pay.x = (unsigned)v0; pay.y = (unsigned)v1;
      pay.z = (unsigned)v2; pay.w = (unsigned)v3;
      *(uint4*)(ldsW + parity) = pay;
    }
    __syncthreads();
    f32x4 acc0, acc1;
    acc0[0] = bias[0][0]; acc0[1] = bias[0][1]; acc0[2] = bias[0][2]; acc0[3] = bias[0][3];
    acc1[0] = bias[1][0]; acc1[1] = bias[1][1]; acc1[2] = bias[1][2]; acc1[3] = bias[1][3];
    #pragma unroll
    for (int oz = 0; oz < 5; ++oz) {
      acc0 = __builtin_amdgcn_mfma_f32_16x16x32_bf16(afr[0][8 + oz], zf[oz], acc0, 0, 0, 0);
      acc1 = __builtin_amdgcn_mfma_f32_16x16x32_bf16(afr[1][8 + oz], zf[oz], acc1, 0, 0, 0);
    }
    #pragma unroll
    for (int o = 0; o < 8; ++o) {
      bf16x8 hf = *(const bf16x8*)(sHb + parity + (bl << 9) + ((((o << 2) + kg) ^ bl) << 4));
      acc0 = __builtin_amdgcn_mfma_f32_16x16x32_bf16(afr[0][o], hf, acc0, 0, 0, 0);
      acc1 = __builtin_amdgcn_mfma_f32_16x16x32_bf16(afr[1][o], hf, acc1, 0, 0, 0);
    }
    #pragma unroll
    for (int a = 0; a < 2; ++a) {
      const f32x4 acc = a ? acc1 : acc0;
      cs[a] = sigm(acc[1]) * cs[a] + sigm(acc[0]) * tanh_f(acc[2]);
      const float hv = sigm(acc[3]) * tanh_f(cs[a]);
      const float hp = __shfl_xor(hv, 16);
      const int j = jt * 64 + ((w << 1) + a) * 4 + kg;
      if (t < TLEN - 1) {
        if (!(kg & 1)) {
          const unsigned d = (unsigned)f2bf(hv) | ((unsigned)f2bf(hp) << 16);
          const unsigned long long pk = ((unsigned long long)(unsigned)(t + 1) << 32) | d;
          __hip_atomic_store(hq + (size_t)bufW * 8192 + (size_t)b * 128 + (j >> 1),
                             pk, __ATOMIC_RELAXED, __HIP_MEMORY_SCOPE_AGENT);
        }
      } else {
        hfin[b * 256 + j] = hv;
      }
    }
  }
}

// K4: head
__global__ __launch_bounds__(256) void head_kernel(
    const float* __restrict__ hfin, const float* __restrict__ o1w,
    const float* __restrict__ o1b, const float* __restrict__ o2w,
    const float* __restrict__ o2b, float* __restrict__ out)
{
  __shared__ float sR[32];
  const int b = blockIdx.x;
  const int tid = threadIdx.x;
  const int m = tid >> 3, g = tid & 7;
  const float* h = hfin + b * 256;
  float acc = 0.f;
  for (int k = g * 32; k < g * 32 + 32; ++k) acc += h[k] * o1w[m * 256 + k];
  acc += __shfl_xor(acc, 1); acc += __shfl_xor(acc, 2); acc += __shfl_xor(acc, 4);
  if (g == 0) sR[m] = fmaxf(acc + o1b[m], 0.f);
  __syncthreads();
  if (tid == 0) {
    float s = o2b[0];
    for (int mm = 0; mm < 32; ++mm) s += sR[mm] * o2w[mm];
    out[b] = sigm(s);
  }
}

extern "C" void kernel_launch(void* const* d_in, const int* in_sizes, int n_in,
                              void* d_out, int out_size, void* d_ws, size_t ws_size,
                              hipStream_t stream) {
  (void)in_sizes; (void)n_in; (void)out_size;
  const int*   alpha = (const int*)  d_in[0];
  const float* sound = (const float*)d_in[1];
  const float* w1    = (const float*)d_in[2];
  const float* b1    = (const float*)d_in[3];
  const float* w2    = (const float*)d_in[4];
  const float* b2    = (const float*)d_in[5];
  const float* w3    = (const float*)d_in[6];
  const float* b3    = (const float*)d_in[7];
  const float* linw  = (const float*)d_in[8];
  const float* linb  = (const float*)d_in[9];
  const float* wih   = (const float*)d_in[10];
  const float* whh   = (const float*)d_in[11];
  const float* bih   = (const float*)d_in[12];
  const float* bhh   = (const float*)d_in[13];
  const float* o1w   = (const float*)d_in[14];
  const float* o1b   = (const float*)d_in[15];
  const float* o2w   = (const float*)d_in[16];
  const float* o2b   = (const float*)d_in[17];

  // byte layout (16B-aligned)
  char* p = (char*)d_ws;
  unsigned short* zw     = (unsigned short*)p;              // 5,242,880 B
  float*          Wc     = (float*)(p + 5242880);           //   540,672 B
  float*          bc     = (float*)(p + 5783552);           //     4,096 B
  float*          w3t    = (float*)(p + 5787648);           //    49,152 B
  float*          hfin   = (float*)(p + 5836800);           //    65,536 B
  unsigned short* Wcperm = (unsigned short*)(p + 5902336);  //   327,680 B
  float*          bcp    = (float*)(p + 6230016);           //     4,096 B
  unsigned short* whhp   = (unsigned short*)(p + 6234112);  //   524,288 B
  unsigned short* xwp    = (unsigned short*)(p + 6758400);  // 33,554,432 B -> end 40,312,832

  prep_kernel<<<1024, 256, 0, stream>>>(wih, linw, linb, bih, bhh, Wc, bc);
  transpose_w3<<<48, 256, 0, stream>>>(w3, w3t);
  conv_kernel<<<BSZ * TLEN, 64, 0, stream>>>(alpha, sound, w1, b1, w2, b2, w3t, b3, zw);

  if (ws_size >= 40312832ull) {
    pack_wc<<<80, 256, 0, stream>>>(Wc, bc, Wcperm, bcp);
    pack_whh<<<128, 256, 0, stream>>>(whh, whhp);
    xw_gemm<<<TLEN * 4, 256, 0, stream>>>(zw, Wcperm, bcp, xwp);
    lstm_kernel<<<4, 512, 0, stream>>>(whhp, xwp, hfin);
  } else {
    unsigned long long* hq = (unsigned long long*)(p + 5902336);
    hipMemsetAsync(p + 5902336, 0, 196608, stream);
    lstm_mailbox<<<16, 512, 0, stream>>>(zw, Wc, bc, whh, hq, hfin);
  }
  head_kernel<<<BSZ, 256, 0, stream>>>(hfin, o1w, o1b, o2w, o2b, (float*)d_out);
}

// Round 10
// 989.589 us; speedup vs baseline: 1.6134x; 1.6134x over previous
//
#include <hip/hip_runtime.h>
#include <math.h>

#define BSZ 64
#define TLEN 256
#define LSND 65536
#define ZK 160            // z K-length in bf16 slots: 129 real + iv-residual@129 + pads

typedef __attribute__((ext_vector_type(8))) short bf16x8;
typedef __attribute__((ext_vector_type(4))) float f32x4;

__device__ __forceinline__ float sigm(float x) { return 1.f / (1.f + __expf(-x)); }
__device__ __forceinline__ float tanh_f(float x) {
  float e = __expf(-2.f * fabsf(x));
  return copysignf((1.f - e) / (1.f + e), x);
}
__device__ __forceinline__ unsigned short f2bf(float x) {   // RNE f32->bf16
  unsigned u = __float_as_uint(x);
  return (unsigned short)((u + 0x7FFFu + ((u >> 16) & 1u)) >> 16);
}
__device__ __forceinline__ f32x4 unpack4(unsigned long long v) {
  f32x4 r;
  r[0] = __uint_as_float((unsigned)(v & 0xFFFFu) << 16);
  r[1] = __uint_as_float((unsigned)((v >> 16) & 0xFFFFu) << 16);
  r[2] = __uint_as_float((unsigned)((v >> 32) & 0xFFFFu) << 16);
  r[3] = __uint_as_float((unsigned)((v >> 48) & 0xFFFFu) << 16);
  return r;
}
// weight-row permutation: tile row m -> (jl=m>>2, gate=m&3); n = gate*256 + q*4 + jl
__device__ __forceinline__ int nrow(int q, int m) {
  return ((m & 3) << 8) + (q << 2) + (m >> 2);
}

// K1: fold linear into w_ih: Wc[n][j] (1024x132, cols>=129 zero); bc = folded bias
__global__ __launch_bounds__(256) void prep_kernel(
    const float* __restrict__ w_ih, const float* __restrict__ lin_w,
    const float* __restrict__ lin_b, const float* __restrict__ b_ih,
    const float* __restrict__ b_hh, float* __restrict__ Wc, float* __restrict__ bc)
{
  __shared__ float sRow[256];
  const int n = blockIdx.x;
  const int j = threadIdx.x;
  sRow[j] = w_ih[n * 256 + j];
  __syncthreads();
  if (j < 132) {
    float acc = 0.f;
    if (j < 129) {
      for (int k = 0; k < 256; ++k) acc += sRow[k] * lin_w[k * 129 + j];
    }
    Wc[n * 132 + j] = acc;
  } else if (j == 255) {
    float acc = b_ih[n] + b_hh[n];
    for (int k = 0; k < 256; ++k) acc += sRow[k] * lin_b[k];
    bc[n] = acc;
  }
}

__global__ __launch_bounds__(256) void transpose_w3(const float* __restrict__ w3,
                                                    float* __restrict__ w3t)
{
  int i = blockIdx.x * 256 + threadIdx.x;
  if (i < 96 * 128) { int s = i >> 7, o = i & 127; w3t[i] = w3[o * 96 + s]; }
}

// K1c: pack Wc into MFMA-A-frag chunks (bf16) + permuted bias
__global__ __launch_bounds__(256) void pack_wc(
    const float* __restrict__ Wc, const float* __restrict__ bc,
    unsigned short* __restrict__ Wcperm, float* __restrict__ bcp)
{
  const int cid = blockIdx.x * 256 + threadIdx.x;
  if (cid >= 64 * 5 * 64) return;
  const int q = cid / 320, rem = cid - q * 320;
  const int o = rem >> 6, l = rem & 63;
  const int m = l >> 2, kg = l & 3;
  const int n = nrow(q, m);
  unsigned short out[8];
  #pragma unroll
  for (int e = 0; e < 8; ++e) {
    const int kz = o * 32 + kg * 8 + e;
    float v = (kz < 129) ? Wc[n * 132 + kz] : (kz == 129 ? Wc[n * 132] : 0.f);
    out[e] = f2bf(v);
  }
  *(ulonglong2*)(Wcperm + cid * 8) = *(ulonglong2*)out;
  if (o == 0 && kg == 0) bcp[q * 16 + m] = bc[n];
}

// K1d: pack w_hh into A-frag chunks: chunk id = ((q*8+o)*16+m)*4+kg
__global__ __launch_bounds__(256) void pack_whh(
    const float* __restrict__ whh, unsigned short* __restrict__ whhp)
{
  const int cid = blockIdx.x * 256 + threadIdx.x;   // < 32768
  const int q = cid >> 9, rem = cid & 511;
  const int o = rem >> 6, l = rem & 63;
  const int m = l >> 2, kg = l & 3;
  const int n = nrow(q, m);
  unsigned short out[8];
  #pragma unroll
  for (int e = 0; e < 8; ++e)
    out[e] = f2bf(whh[n * 256 + o * 32 + kg * 8 + e]);
  *(ulonglong2*)(whhp + cid * 8) = *(ulonglong2*)out;
}

// K2: gather + conv1/conv2/conv3 -> zw[t][b][ZK] bf16 (R7 verbatim).
__global__ __launch_bounds__(64) void conv_kernel(
    const int* __restrict__ alpha, const float* __restrict__ sound,
    const float* __restrict__ w1, const float* __restrict__ b1v,
    const float* __restrict__ w2, const float* __restrict__ b2,
    const float* __restrict__ w3t, const float* __restrict__ b3,
    unsigned short* __restrict__ zw)
{
  __shared__ float win[2048];
  __shared__ float sY2[96];
  const int l = threadIdx.x;
  const int b = blockIdx.x >> 8;
  const int t = blockIdx.x & 255;
  const int a = alpha[b * TLEN + t];
  const int a0 = a - 1024;
  const float* srow = sound + (size_t)b * LSND;
  for (int x = l; x < 2048; x += 64) {
    int p = a0 + x;
    win[x] = (p >= 0 && p < LSND) ? srow[p] : 0.f;
  }
  __syncthreads();
  float acc0 = 0.f, acc1 = 0.f, acc2 = 0.f;
  for (int f = l; f < 2046; f += 64) {
    float wv = w1[f];
    acc0 += win[f] * wv;
    acc1 += win[f + 1] * wv;
    acc2 += win[f + 2] * wv;
  }
  for (int m = 32; m; m >>= 1) {
    acc0 += __shfl_xor(acc0, m);
    acc1 += __shfl_xor(acc1, m);
    acc2 += __shfl_xor(acc2, m);
  }
  const float bb = b1v[0];
  const float y11 = acc0 + bb, y12 = acc1 + bb, y13 = acc2 + bb;
  {
    int s = l;
    int c = s / 3, lp = s - c * 3;
    float wA = w2[c * 3], wB = w2[c * 3 + 1], wC = w2[c * 3 + 2];
    float v = (lp == 0) ? (y11 * wB + y12 * wC)
            : (lp == 1) ? (y11 * wA + y12 * wB + y13 * wC)
                        : (y12 * wA + y13 * wB);
    sY2[s] = fmaxf(v + b2[c], 0.f);
    if (l < 32) {
      s = 64 + l; c = s / 3; lp = s - c * 3;
      wA = w2[c * 3]; wB = w2[c * 3 + 1]; wC = w2[c * 3 + 2];
      v = (lp == 0) ? (y11 * wB + y12 * wC)
        : (lp == 1) ? (y11 * wA + y12 * wB + y13 * wC)
                    : (y12 * wA + y13 * wB);
      sY2[s] = fmaxf(v + b2[c], 0.f);
    }
  }
  __syncthreads();
  float o0 = b3[l], o1 = b3[l + 64];
  for (int s = 0; s < 96; ++s) {
    float yv = sY2[s];
    o0 += yv * w3t[s * 128 + l];
    o1 += yv * w3t[s * 128 + l + 64];
  }
  unsigned short* zrow = zw + ((size_t)t * BSZ + b) * ZK;
  zrow[1 + l] = f2bf(o0);
  zrow[65 + l] = f2bf(o1);
  if (l == 0) {
    int prev = (t > 0) ? alpha[b * TLEN + t - 1] : 0;
    float iv = (float)(a - prev);
    unsigned short hi = f2bf(iv);
    zrow[0] = hi;
    float rec = __uint_as_float(((unsigned)hi) << 16);
    zrow[129] = f2bf(iv - rec);
  }
  if (l < 30) zrow[130 + l] = 0;
}

// K2b: xw GEMM (R8 verbatim, numerics proven): xw[t][b][n] = z.Wc^T + bc, bf16,
// frag-linear: 16B chunk c = q*32 + bl*2 + (kg>>1) within [t][bt] 32KB block.
__global__ __launch_bounds__(256) void xw_gemm(
    const unsigned short* __restrict__ zw, const unsigned short* __restrict__ Wcperm,
    const float* __restrict__ bcp, unsigned short* __restrict__ xwp)
{
  const int t = (int)blockIdx.x >> 2;
  const int bt = (int)blockIdx.x & 3;
  const int tid = threadIdx.x;
  const int w = tid >> 6, ln = tid & 63;
  const int bl = ln & 15, kg = ln >> 4;

  bf16x8 zf[5];
  #pragma unroll
  for (int o = 0; o < 5; ++o)
    zf[o] = *(const bf16x8*)(zw + ((size_t)t * BSZ + (bt << 4) + bl) * ZK + o * 32 + kg * 8);

  #pragma unroll 2
  for (int qq = 0; qq < 16; ++qq) {
    const int q = (w << 4) + qq;
    f32x4 acc = *(const f32x4*)(bcp + q * 16 + (kg << 2));
    #pragma unroll
    for (int o = 0; o < 5; ++o) {
      bf16x8 af = *(const bf16x8*)(Wcperm + ((size_t)(q * 5 + o) * 64 + (bl << 2) + kg) * 8);
      acc = __builtin_amdgcn_mfma_f32_16x16x32_bf16(af, zf[o], acc, 0, 0, 0);
    }
    uint2 pk;
    pk.x = (unsigned)f2bf(acc[0]) | ((unsigned)f2bf(acc[1]) << 16);
    pk.y = (unsigned)f2bf(acc[2]) | ((unsigned)f2bf(acc[3]) << 16);
    char* dst = (char*)xwp + (((size_t)t * 4 + bt) << 15)
              + ((q * 32 + bl * 2 + (kg >> 1)) << 4) + ((kg & 1) << 3);
    *(uint2*)dst = pk;
  }
}

// K3: pairwise MFMA LSTM. 8 blocks (bt 0..3 x jh 0..1) x 512 thr, launch_bounds(512,1)
// -> 256-VGPR cap. Block owns 16 b x 128 j x 4 gates; w_hh slice fully register-
// resident (32 frags = 128 VGPR). Own h-half recirculates through LDS only; the
// OTHER half comes from exactly ONE partner block (bid^1) via agent-scope tagged
// u64 mailboxes {tag32|2xbf16} (R3/R5/R7-proven semantics, payload rides the poll).
// 2-buffer rotation (pairwise-causal safe). Bounded poll: breaks (wrong answer,
// no hang) after 2^20 sweeps. One __syncthreads per step. xw precomputed (K2b).
__global__ void __launch_bounds__(512, 1) lstm_kernel(
    const unsigned short* __restrict__ whhp, const unsigned short* __restrict__ xwp,
    unsigned long long* __restrict__ hq, float* __restrict__ hfin)
{
  __shared__ unsigned short sH[2][16][256];   // [parity][b][j], 16B-slot XOR swizzle
  char* sHb = (char*)sH;

  const int tid = threadIdx.x;
  const int w = tid >> 6, ln = tid & 63;
  const int bl = ln & 15, kg = ln >> 4;
  const int bid = (int)blockIdx.x;            // 0..7
  const int bt = bid >> 1, jh = bid & 1;
  const int b = (bt << 4) + bl;
  const int pb = (jh ^ 1) << 7;               // partner j-base

  // ---- weights: 4 q-tiles x 8 k-frags, all in VGPRs ----
  bf16x8 wfr[4][8];
  #pragma unroll
  for (int q = 0; q < 4; ++q) {
    const int qg = (jh << 5) + (w << 2) + q;
    #pragma unroll
    for (int o = 0; o < 8; ++o)
      wfr[q][o] = *(const bf16x8*)(whhp + (((size_t)(qg * 8 + o) * 16 + bl) * 4 + kg) * 8);
  }

  // zero both LDS parities (h(0) = 0)
  for (int i = tid; i < 4096; i += 512) ((unsigned*)sHb)[i] = 0;

  // poll role: lane tid covers partner words 2*tid, 2*tid+1
  // word idx = b_local*64 + j_pair  ->  4 consecutive j per lane (8B in LDS)
  const int prow = tid >> 5;
  const int pj0 = pb + ((tid & 31) << 2);
  char* pdst = sHb + (prow << 9) + (((pj0 >> 3) ^ prow) << 4) + ((pj0 & 7) << 1);
  float cs[4] = {0.f, 0.f, 0.f, 0.f};

  #pragma unroll 1
  for (int t = 0; t < TLEN; ++t) {
    const int p_ = (t & 1) << 13;

    // xw loads for this step (latency hidden under the poll)
    unsigned long long xwv[4];
    {
      const char* xb = (const char*)xwp + (((size_t)t * 4 + bt) << 15) + ((kg & 1) << 3);
      #pragma unroll
      for (int q = 0; q < 4; ++q) {
        const int chunk = (((jh << 5) + (w << 2) + q) << 5) + (bl << 1) + (kg >> 1);
        xwv[q] = *(const unsigned long long*)(xb + (chunk << 4));
      }
    }

    // poll partner half of h(t); payload rides the load; bounded
    if (t > 0) {
      const unsigned long long* hs =
          hq + ((size_t)(t & 1)) * 8192 + ((size_t)(bid ^ 1) << 10) + (tid << 1);
      const unsigned tagw = (unsigned)t;
      unsigned long long v0 =
          __hip_atomic_load(hs, __ATOMIC_RELAXED, __HIP_MEMORY_SCOPE_AGENT);
      unsigned long long v1 =
          __hip_atomic_load(hs + 1, __ATOMIC_RELAXED, __HIP_MEMORY_SCOPE_AGENT);
      int guard = 0;
      for (;;) {
        bool ok = true;
        if ((unsigned)(v0 >> 32) != tagw) {
          v0 = __hip_atomic_load(hs, __ATOMIC_RELAXED, __HIP_MEMORY_SCOPE_AGENT);
          ok = false;
        }
        if ((unsigned)(v1 >> 32) != tagw) {
          v1 = __hip_atomic_load(hs + 1, __ATOMIC_RELAXED, __HIP_MEMORY_SCOPE_AGENT);
          ok = false;
        }
        if (ok || ++guard > (1 << 20)) break;
      }
      uint2 pay;
      pay.x = (unsigned)v0;
      pay.y = (unsigned)v1;
      *(uint2*)(pdst + p_) = pay;             // partner 4 j's into LDS
    }
    __syncthreads();                          // all h(t) in LDS[p_]

    // h B-frags (shared across q-tiles)
    bf16x8 hf[8];
    #pragma unroll
    for (int o = 0; o < 8; ++o)
      hf[o] = *(const bf16x8*)(sHb + p_ + (bl << 9) + ((((o << 2) + kg) ^ bl) << 4));

    #pragma unroll
    for (int q = 0; q < 4; ++q) {
      f32x4 acc = unpack4(xwv[q]);
      #pragma unroll
      for (int o = 0; o < 8; ++o)
        acc = __builtin_amdgcn_mfma_f32_16x16x32_bf16(wfr[q][o], hf[o], acc, 0, 0, 0);
      // gates: lane owns (b=bl, j) with all 4 gates in acc[0..3]
      cs[q] = sigm(acc[1]) * cs[q] + sigm(acc[0]) * tanh_f(acc[2]);
      const float hv = sigm(acc[3]) * tanh_f(cs[q]);
      const float hp = __shfl_xor(hv, 16);    // kg^1 partner (j+-1)
      const int jloc = (w << 4) + (q << 2) + kg;
      const int jglob = (jh << 7) + jloc;
      if (t < TLEN - 1) {
        if (!(kg & 1)) {
          const unsigned d = (unsigned)f2bf(hv) | ((unsigned)f2bf(hp) << 16);
          // own half -> LDS parity^1
          *(unsigned*)(sHb + (p_ ^ 8192) + (bl << 9)
                       + (((jglob >> 3) ^ bl) << 4) + ((jglob & 7) << 1)) = d;
          // publish to partner (fire-and-forget)
          const unsigned long long pk =
              ((unsigned long long)(unsigned)(t + 1) << 32) | d;
          __hip_atomic_store(hq + ((size_t)((t + 1) & 1)) * 8192 + ((size_t)bid << 10)
                                 + (bl << 6) + (jloc >> 1),
                             pk, __ATOMIC_RELAXED, __HIP_MEMORY_SCOPE_AGENT);
        }
      } else {
        hfin[b * 256 + jglob] = hv;
      }
    }
  }
}

// K4: head
__global__ __launch_bounds__(256) void head_kernel(
    const float* __restrict__ hfin, const float* __restrict__ o1w,
    const float* __restrict__ o1b, const float* __restrict__ o2w,
    const float* __restrict__ o2b, float* __restrict__ out)
{
  __shared__ float sR[32];
  const int b = blockIdx.x;
  const int tid = threadIdx.x;
  const int m = tid >> 3, g = tid & 7;
  const float* h = hfin + b * 256;
  float acc = 0.f;
  for (int k = g * 32; k < g * 32 + 32; ++k) acc += h[k] * o1w[m * 256 + k];
  acc += __shfl_xor(acc, 1); acc += __shfl_xor(acc, 2); acc += __shfl_xor(acc, 4);
  if (g == 0) sR[m] = fmaxf(acc + o1b[m], 0.f);
  __syncthreads();
  if (tid == 0) {
    float s = o2b[0];
    for (int mm = 0; mm < 32; ++mm) s += sR[mm] * o2w[mm];
    out[b] = sigm(s);
  }
}

extern "C" void kernel_launch(void* const* d_in, const int* in_sizes, int n_in,
                              void* d_out, int out_size, void* d_ws, size_t ws_size,
                              hipStream_t stream) {
  (void)in_sizes; (void)n_in; (void)out_size; (void)ws_size;
  const int*   alpha = (const int*)  d_in[0];
  const float* sound = (const float*)d_in[1];
  const float* w1    = (const float*)d_in[2];
  const float* b1    = (const float*)d_in[3];
  const float* w2    = (const float*)d_in[4];
  const float* b2    = (const float*)d_in[5];
  const float* w3    = (const float*)d_in[6];
  const float* b3    = (const float*)d_in[7];
  const float* linw  = (const float*)d_in[8];
  const float* linb  = (const float*)d_in[9];
  const float* wih   = (const float*)d_in[10];
  const float* whh   = (const float*)d_in[11];
  const float* bih   = (const float*)d_in[12];
  const float* bhh   = (const float*)d_in[13];
  const float* o1w   = (const float*)d_in[14];
  const float* o1b   = (const float*)d_in[15];
  const float* o2w   = (const float*)d_in[16];
  const float* o2b   = (const float*)d_in[17];

  // byte layout (16B-aligned). hq reuses the Wcperm region: memset AFTER xw_gemm
  // (stream-ordered), since Wcperm/bcp are dead once xw_gemm completes.
  char* p = (char*)d_ws;
  unsigned short* zw     = (unsigned short*)p;              // 5,242,880 B
  float*          Wc     = (float*)(p + 5242880);           //   540,672 B
  float*          bc     = (float*)(p + 5783552);           //     4,096 B
  float*          w3t    = (float*)(p + 5787648);           //    49,152 B
  float*          hfin   = (float*)(p + 5836800);           //    65,536 B
  unsigned short* Wcperm = (unsigned short*)(p + 5902336);  //   327,680 B (later: hq)
  float*          bcp    = (float*)(p + 6230016);           //     4,096 B
  unsigned short* whhp   = (unsigned short*)(p + 6234112);  //   524,288 B
  unsigned short* xwp    = (unsigned short*)(p + 6758400);  // 33,554,432 B -> 40,312,832
  unsigned long long* hq = (unsigned long long*)(p + 5902336);  // 2*8192 u64 = 131,072 B

  prep_kernel<<<1024, 256, 0, stream>>>(wih, linw, linb, bih, bhh, Wc, bc);
  transpose_w3<<<48, 256, 0, stream>>>(w3, w3t);
  conv_kernel<<<BSZ * TLEN, 64, 0, stream>>>(alpha, sound, w1, b1, w2, b2, w3t, b3, zw);
  pack_wc<<<80, 256, 0, stream>>>(Wc, bc, Wcperm, bcp);
  pack_whh<<<128, 256, 0, stream>>>(whh, whhp);
  xw_gemm<<<TLEN * 4, 256, 0, stream>>>(zw, Wcperm, bcp, xwp);
  hipMemsetAsync(hq, 0, 131072, stream);      // tags=0 (Wcperm dead from here)
  lstm_kernel<<<8, 512, 0, stream>>>(whhp, xwp, hq, hfin);
  head_kernel<<<BSZ, 256, 0, stream>>>(hfin, o1w, o1b, o2w, o2b, (float*)d_out);
}